// Round 2
// baseline (1640.570 us; speedup 1.0000x reference)
//
#include <hip/hip_runtime.h>
#include <math.h>

// AutoLUT forward, MI355X. B=4, N=512, K=3 (PAD=2), Q=16, L=17, UPSCALE=4, SAMPLERS=3.
static constexpr int B_ = 4;
static constexpr int N_ = 512;
static constexpr int N4_ = 2048;
static constexpr int LUT_ROWS = 83521;         // 17^4
static constexpr int ST0 = 4913, ST1 = 289, ST2 = 17, ST3 = 1;

__device__ __forceinline__ float fixw(float v) {
    v = rintf(v * 127.0f);
    return fminf(fmaxf(v, -127.0f), 127.0f);
}

__global__ void fix_lut_kernel(const float* __restrict__ in, float* __restrict__ out, int n) {
    int idx = blockIdx.x * blockDim.x + threadIdx.x;
    int gsz = gridDim.x * blockDim.x;
    for (int t = idx; t < n; t += gsz) out[t] = fixw(in[t]);
}

struct Simplex {
    int v[5];
    float w[5];
};

// 4-D simplex lookup setup. floor/mod by 16 are exact in fp32 (pow-2); sort is a
// stable descending bubble network (ties -> zero-weight vertices, order-irrelevant).
__device__ __forceinline__ Simplex simplex4(float a, float b, float c, float d) {
    float fl0 = floorf(a * 0.0625f), fl1 = floorf(b * 0.0625f),
          fl2 = floorf(c * 0.0625f), fl3 = floorf(d * 0.0625f);
    float f[4] = { a - 16.0f * fl0, b - 16.0f * fl1, c - 16.0f * fl2, d - 16.0f * fl3 };
    int l0 = min(max((int)fl0, 0), 15);
    int l1 = min(max((int)fl1, 0), 15);
    int l2 = min(max((int)fl2, 0), 15);
    int l3 = min(max((int)fl3, 0), 15);
    int st[4] = { ST0, ST1, ST2, ST3 };
#define CSW(A, Bq) { if (f[A] < f[Bq]) { float tf = f[A]; f[A] = f[Bq]; f[Bq] = tf; \
                                         int ts = st[A]; st[A] = st[Bq]; st[Bq] = ts; } }
    CSW(0, 1) CSW(1, 2) CSW(2, 3) CSW(0, 1) CSW(1, 2) CSW(0, 1)
#undef CSW
    Simplex s;
    s.v[0] = l0 * ST0 + l1 * ST1 + l2 * ST2 + l3;
    s.v[1] = s.v[0] + st[0];
    s.v[2] = s.v[1] + st[1];
    s.v[3] = s.v[2] + st[2];
    s.v[4] = s.v[3] + st[3];
    s.w[0] = 16.0f - f[0];
    s.w[1] = f[0] - f[1];
    s.w[2] = f[1] - f[2];
    s.w[3] = f[2] - f[3];
    s.w[4] = f[3];
    return s;
}

// Per-rotation tap remap: rotation r + pad-bottom/right(edge) + VALID conv +
// rotate-back collapses to clamped neighborhood reads in the original frame.
__device__ __forceinline__ void tapmap(int r, int di, int dj, int& pa, int& pb) {
    if (r == 0)      { pa = 2 + di; pb = 2 + dj; }
    else if (r == 1) { pa = 2 + dj; pb = 2 - di; }
    else if (r == 2) { pa = 2 - di; pb = 2 - dj; }
    else             { pa = 2 - dj; pb = 2 + di; }
}

template <bool PF>
__global__ __launch_bounds__(256, 4) void stage0_kernel(
    const float* __restrict__ x,       // (4,512,512), [0,1]
    const float* __restrict__ lut0,    // (3,83521) fixed (or raw if !PF)
    const float* __restrict__ samp0,   // (3,4,3,3)
    const float* __restrict__ sbias0,  // (3,4)
    float* __restrict__ x1)            // out: (4,512,512), integer-valued 0..255
{
    int tid = blockIdx.x * blockDim.x + threadIdx.x;
    if (tid >= B_ * N_ * N_) return;
    int j = tid & (N_ - 1);
    int i = (tid >> 9) & (N_ - 1);
    int b = tid >> 18;

    float nb[5][5];
    const float* xb = x + (size_t)b * N_ * N_;
    #pragma unroll
    for (int a = 0; a < 5; ++a) {
        int ri = min(max(i - 2 + a, 0), N_ - 1);
        #pragma unroll
        for (int c = 0; c < 5; ++c) {
            int ci = min(max(j - 2 + c, 0), N_ - 1);
            nb[a][c] = xb[ri * N_ + ci] * 255.0f;
        }
    }

    float pred = 0.0f;
    for (int s = 0; s < 3; ++s) {
        const float* w  = samp0 + s * 36;
        const float* sb = sbias0 + s * 4;
        const float* lut = lut0 + (size_t)s * LUT_ROWS;

        // conv phase: all 16 (r,ch) values first, so nb can die before gathers
        float vals[4][4];
        #pragma unroll
        for (int r = 0; r < 4; ++r)
            #pragma unroll
            for (int ch = 0; ch < 4; ++ch) {
                float v = 0.0f;
                #pragma unroll
                for (int di = 0; di < 3; ++di)
                    #pragma unroll
                    for (int dj = 0; dj < 3; ++dj) {
                        int pa, pb;
                        tapmap(r, di, dj, pa, pb);
                        v += w[ch * 9 + di * 3 + dj] * nb[pa][pb];
                    }
                vals[r][ch] = v + sb[ch];
            }

        float acc = 0.0f;
        #pragma unroll
        for (int r = 0; r < 4; ++r) {
            Simplex sx = simplex4(vals[r][0], vals[r][1], vals[r][2], vals[r][3]);
            float o = 0.0f;
            #pragma unroll
            for (int v = 0; v < 5; ++v) {
                float p = lut[sx.v[v]];
                if (!PF) p = fixw(p);
                o += sx.w[v] * p;
            }
            acc = rintf(acc + o * 0.0625f);   // ste_round after each rotation
        }
        pred += acc;
    }
    x1[tid] = rintf(fminf(fmaxf(pred / 12.0f + 127.0f, 0.0f), 255.0f));
}

template <bool PF>
__global__ __launch_bounds__(256, 3) void stage1_kernel(
    const float* __restrict__ x,       // original (4,512,512), [0,1]
    const float* __restrict__ x1,      // stage-0 out, 0..255
    const float* __restrict__ lut1,    // (3,83521,16) fixed (or raw if !PF)
    const float* __restrict__ samp1,   // (3,4,3,3)
    const float* __restrict__ sbias1,  // (3,4)
    const float* __restrict__ resw1,   // (3,2,2)
    float* __restrict__ out)           // (4,2048,2048)
{
    int tid = blockIdx.x * blockDim.x + threadIdx.x;
    if (tid >= B_ * N_ * N_) return;
    int j = tid & (N_ - 1);
    int i = (tid >> 9) & (N_ - 1);
    int b = tid >> 18;

    float tot[16];
    #pragma unroll
    for (int k = 0; k < 16; ++k) tot[k] = 0.0f;

    for (int s = 0; s < 3; ++s) {
        const float* w  = samp1 + s * 36;
        const float* sb = sbias1 + s * 4;
        const float* lut = lut1 + (size_t)s * LUT_ROWS * 16;
        float rw[4];
        #pragma unroll
        for (int ch = 0; ch < 4; ++ch)
            rw[ch] = fminf(fmaxf(resw1[s * 4 + ch], 0.0f), 1.0f);

        // ---- conv phase: load neighborhoods (re-read per sampler; L1-hot),
        // compute all 16 blended conv values, then the 50 nb regs are dead.
        float vals[4][4];
        {
            float nc[5][5], np[5][5];
            const float* xb  = x  + (size_t)b * N_ * N_;
            const float* x1b = x1 + (size_t)b * N_ * N_;
            #pragma unroll
            for (int a = 0; a < 5; ++a) {
                int ri = min(max(i - 2 + a, 0), N_ - 1);
                #pragma unroll
                for (int c = 0; c < 5; ++c) {
                    int ci = min(max(j - 2 + c, 0), N_ - 1);
                    nc[a][c] = x1b[ri * N_ + ci];
                    np[a][c] = xb[ri * N_ + ci] * 255.0f;
                }
            }
            #pragma unroll
            for (int r = 0; r < 4; ++r)
                #pragma unroll
                for (int ch = 0; ch < 4; ++ch) {
                    float vc = 0.0f, vp = 0.0f;
                    #pragma unroll
                    for (int di = 0; di < 3; ++di)
                        #pragma unroll
                        for (int dj = 0; dj < 3; ++dj) {
                            int pa, pb;
                            tapmap(r, di, dj, pa, pb);
                            float wt = w[ch * 9 + di * 3 + dj];
                            vc += wt * nc[pa][pb];
                            vp += wt * np[pa][pb];
                        }
                    vc += sb[ch];
                    vp += sb[ch];
                    vals[r][ch] = rw[ch] * vp + (1.0f - rw[ch]) * vc;
                }
        }

        // ---- gather/interp phase
        float acc[16];
        #pragma unroll
        for (int k = 0; k < 16; ++k) acc[k] = 0.0f;

        #pragma unroll
        for (int r = 0; r < 4; ++r) {
            Simplex sx = simplex4(vals[r][0], vals[r][1], vals[r][2], vals[r][3]);
            float oc[16];
            #pragma unroll
            for (int k = 0; k < 16; ++k) oc[k] = 0.0f;
            // row-by-row accumulate: only one 64B row (4x float4) in regs per step
            #pragma unroll
            for (int v = 0; v < 5; ++v) {
                const float4* rp = (const float4*)(lut + (size_t)sx.v[v] * 16);
                float4 q0 = rp[0], q1 = rp[1], q2 = rp[2], q3 = rp[3];
                float q[16] = { q0.x, q0.y, q0.z, q0.w, q1.x, q1.y, q1.z, q1.w,
                                q2.x, q2.y, q2.z, q2.w, q3.x, q3.y, q3.z, q3.w };
                float wv = sx.w[v];
                #pragma unroll
                for (int k = 0; k < 16; ++k) {
                    float p = q[k];
                    if (!PF) p = fixw(p);
                    oc[k] += wv * p;
                }
            }
            // scatter rotated 4x4 sub-block into original-orientation accumulator
            #pragma unroll
            for (int u = 0; u < 4; ++u)
                #pragma unroll
                for (int v2 = 0; v2 < 4; ++v2) {
                    int k = 4 * u + v2;
                    int c = (r == 0) ? (4 * u + v2)
                          : (r == 1) ? (4 * (3 - v2) + u)
                          : (r == 2) ? (4 * (3 - u) + (3 - v2))
                                     : (4 * v2 + (3 - u));
                    acc[k] = rintf(acc[k] + oc[c] * 0.0625f);   // ste_round per rotation
                }
        }
        #pragma unroll
        for (int k = 0; k < 16; ++k) tot[k] += acc[k];
    }

    float* ob = out + (size_t)b * N4_ * N4_ + (size_t)(i * 4) * N4_ + (j * 4);
    #pragma unroll
    for (int u = 0; u < 4; ++u) {
        float4 val;
        val.x = rintf(fminf(fmaxf(tot[4 * u + 0] / 3.0f, 0.0f), 255.0f)) * (1.0f / 255.0f);
        val.y = rintf(fminf(fmaxf(tot[4 * u + 1] / 3.0f, 0.0f), 255.0f)) * (1.0f / 255.0f);
        val.z = rintf(fminf(fmaxf(tot[4 * u + 2] / 3.0f, 0.0f), 255.0f)) * (1.0f / 255.0f);
        val.w = rintf(fminf(fmaxf(tot[4 * u + 3] / 3.0f, 0.0f), 255.0f)) * (1.0f / 255.0f);
        *(float4*)(ob + (size_t)u * N4_) = val;
    }
}

extern "C" void kernel_launch(void* const* d_in, const int* in_sizes, int n_in,
                              void* d_out, int out_size, void* d_ws, size_t ws_size,
                              hipStream_t stream) {
    const float* x      = (const float*)d_in[0];
    const float* lut0   = (const float*)d_in[1];
    const float* lut1   = (const float*)d_in[2];
    const float* samp0  = (const float*)d_in[3];
    const float* samp1  = (const float*)d_in[4];
    const float* sbias0 = (const float*)d_in[5];
    const float* sbias1 = (const float*)d_in[6];
    const float* resw1  = (const float*)d_in[7];
    float* out = (float*)d_out;
    float* ws  = (float*)d_ws;

    const size_t N_X1 = (size_t)B_ * N_ * N_;       // 1,048,576 floats
    const size_t N_L0 = (size_t)3 * LUT_ROWS;       // 250,563
    const size_t N_L1 = (size_t)3 * LUT_ROWS * 16;  // 4,009,008
    size_t off_x1 = 0;
    size_t off_l0 = N_X1;                           // 4 MB offset, 16B-aligned
    size_t off_l1 = (off_l0 + N_L0 + 3) & ~(size_t)3;
    size_t need_bytes = (off_l1 + N_L1) * sizeof(float);

    float* x1 = ws + off_x1;
    const int threads = 256;
    const int grid = (B_ * N_ * N_) / threads;      // 4096

    if (ws_size >= need_bytes) {
        float* l0f = ws + off_l0;
        float* l1f = ws + off_l1;
        fix_lut_kernel<<<1024, threads, 0, stream>>>(lut0, l0f, (int)N_L0);
        fix_lut_kernel<<<4096, threads, 0, stream>>>(lut1, l1f, (int)N_L1);
        stage0_kernel<true><<<grid, threads, 0, stream>>>(x, l0f, samp0, sbias0, x1);
        stage1_kernel<true><<<grid, threads, 0, stream>>>(x, x1, l1f, samp1, sbias1, resw1, out);
    } else {
        // ws only big enough for x1: fix LUT values on the fly at gather time.
        stage0_kernel<false><<<grid, threads, 0, stream>>>(x, lut0, samp0, sbias0, x1);
        stage1_kernel<false><<<grid, threads, 0, stream>>>(x, x1, lut1, samp1, sbias1, resw1, out);
    }
}

// Round 3
// 370.349 us; speedup vs baseline: 4.4298x; 4.4298x over previous
//
#include <hip/hip_runtime.h>
#include <math.h>

// AutoLUT forward, MI355X. B=4, N=512, K=3 (PAD=2), Q=16, L=17, UPSCALE=4, SAMPLERS=3.
// R3: int8-quantized fixed LUT in ws (exact: fixw values are integers in [-127,127]).
//     Row gather = 16B dwordx4 (was 64B); stage-1 LUT = 4MB -> L2-resident.
static constexpr int B_ = 4;
static constexpr int N_ = 512;
static constexpr int N4_ = 2048;
static constexpr int LUT_ROWS = 83521;         // 17^4
static constexpr int ST0 = 4913, ST1 = 289, ST2 = 17, ST3 = 1;

__device__ __forceinline__ float fixw(float v) {
    v = rintf(v * 127.0f);
    return fminf(fmaxf(v, -127.0f), 127.0f);
}

__global__ void fix_lut0_kernel(const float* __restrict__ in, char* __restrict__ out, int n) {
    int t = blockIdx.x * blockDim.x + threadIdx.x;
    if (t < n) out[t] = (char)(int)fixw(in[t]);
}

__global__ void fix_lut1_kernel(const float4* __restrict__ in, char4* __restrict__ out, int n4) {
    int t = blockIdx.x * blockDim.x + threadIdx.x;
    if (t < n4) {
        float4 v = in[t];
        char4 o;
        o.x = (char)(int)fixw(v.x);
        o.y = (char)(int)fixw(v.y);
        o.z = (char)(int)fixw(v.z);
        o.w = (char)(int)fixw(v.w);
        out[t] = o;
    }
}

struct Simplex {
    int v[5];
    float w[5];
};

// 4-D simplex lookup setup. floor/mod by 16 are exact in fp32 (pow-2); sort is a
// stable descending bubble network (ties -> zero-weight vertices, order-irrelevant).
__device__ __forceinline__ Simplex simplex4(float a, float b, float c, float d) {
    float fl0 = floorf(a * 0.0625f), fl1 = floorf(b * 0.0625f),
          fl2 = floorf(c * 0.0625f), fl3 = floorf(d * 0.0625f);
    float f[4] = { a - 16.0f * fl0, b - 16.0f * fl1, c - 16.0f * fl2, d - 16.0f * fl3 };
    int l0 = min(max((int)fl0, 0), 15);
    int l1 = min(max((int)fl1, 0), 15);
    int l2 = min(max((int)fl2, 0), 15);
    int l3 = min(max((int)fl3, 0), 15);
    int st[4] = { ST0, ST1, ST2, ST3 };
#define CSW(A, Bq) { if (f[A] < f[Bq]) { float tf = f[A]; f[A] = f[Bq]; f[Bq] = tf; \
                                         int ts = st[A]; st[A] = st[Bq]; st[Bq] = ts; } }
    CSW(0, 1) CSW(1, 2) CSW(2, 3) CSW(0, 1) CSW(1, 2) CSW(0, 1)
#undef CSW
    Simplex s;
    s.v[0] = l0 * ST0 + l1 * ST1 + l2 * ST2 + l3;
    s.v[1] = s.v[0] + st[0];
    s.v[2] = s.v[1] + st[1];
    s.v[3] = s.v[2] + st[2];
    s.v[4] = s.v[3] + st[3];
    s.w[0] = 16.0f - f[0];
    s.w[1] = f[0] - f[1];
    s.w[2] = f[1] - f[2];
    s.w[3] = f[2] - f[3];
    s.w[4] = f[3];
    return s;
}

// Per-rotation tap remap: rotation r + pad-bottom/right(edge) + VALID conv +
// rotate-back collapses to clamped neighborhood reads in the original frame.
__device__ __forceinline__ void tapmap(int r, int di, int dj, int& pa, int& pb) {
    if (r == 0)      { pa = 2 + di; pb = 2 + dj; }
    else if (r == 1) { pa = 2 + dj; pb = 2 - di; }
    else if (r == 2) { pa = 2 - di; pb = 2 - dj; }
    else             { pa = 2 - dj; pb = 2 + di; }
}

__device__ __forceinline__ void unpack4(int w, float* o) {
    o[0] = (float)((w << 24) >> 24);
    o[1] = (float)((w << 16) >> 24);
    o[2] = (float)((w << 8) >> 24);
    o[3] = (float)(w >> 24);
}

__global__ __launch_bounds__(256) void stage0_kernel(
    const float* __restrict__ x,       // (4,512,512), [0,1]
    const char* __restrict__ lut0q,    // (3,83521) int8 fixed
    const float* __restrict__ samp0,   // (3,4,3,3)
    const float* __restrict__ sbias0,  // (3,4)
    float* __restrict__ x1)            // out: (4,512,512), integer-valued 0..255
{
    int tid = blockIdx.x * blockDim.x + threadIdx.x;
    if (tid >= B_ * N_ * N_) return;
    int j = tid & (N_ - 1);
    int i = (tid >> 9) & (N_ - 1);
    int b = tid >> 18;

    float nb[5][5];
    const float* xb = x + (size_t)b * N_ * N_;
    #pragma unroll
    for (int a = 0; a < 5; ++a) {
        int ri = min(max(i - 2 + a, 0), N_ - 1);
        #pragma unroll
        for (int c = 0; c < 5; ++c) {
            int ci = min(max(j - 2 + c, 0), N_ - 1);
            nb[a][c] = xb[ri * N_ + ci] * 255.0f;
        }
    }

    float pred = 0.0f;
    for (int s = 0; s < 3; ++s) {
        const float* w  = samp0 + s * 36;
        const float* sb = sbias0 + s * 4;
        const char* lut = lut0q + (size_t)s * LUT_ROWS;
        float acc = 0.0f;
        #pragma unroll
        for (int r = 0; r < 4; ++r) {
            float vals[4];
            #pragma unroll
            for (int ch = 0; ch < 4; ++ch) {
                float v = 0.0f;
                #pragma unroll
                for (int di = 0; di < 3; ++di)
                    #pragma unroll
                    for (int dj = 0; dj < 3; ++dj) {
                        int pa, pb;
                        tapmap(r, di, dj, pa, pb);
                        v += w[ch * 9 + di * 3 + dj] * nb[pa][pb];
                    }
                vals[ch] = v + sb[ch];
            }
            Simplex sx = simplex4(vals[0], vals[1], vals[2], vals[3]);
            float o = 0.0f;
            #pragma unroll
            for (int v = 0; v < 5; ++v)
                o += sx.w[v] * (float)lut[sx.v[v]];
            acc = rintf(acc + o * 0.0625f);   // ste_round after each rotation
        }
        pred += acc;
    }
    x1[tid] = rintf(fminf(fmaxf(pred / 12.0f + 127.0f, 0.0f), 255.0f));
}

__global__ __launch_bounds__(256) void stage1_kernel(
    const float* __restrict__ x,       // original (4,512,512), [0,1]
    const float* __restrict__ x1,      // stage-0 out, 0..255
    const char* __restrict__ lut1q,    // (3,83521,16) int8 fixed
    const float* __restrict__ samp1,   // (3,4,3,3)
    const float* __restrict__ sbias1,  // (3,4)
    const float* __restrict__ resw1,   // (3,2,2)
    float* __restrict__ out)           // (4,2048,2048)
{
    int tid = blockIdx.x * blockDim.x + threadIdx.x;
    if (tid >= B_ * N_ * N_) return;
    int j = tid & (N_ - 1);
    int i = (tid >> 9) & (N_ - 1);
    int b = tid >> 18;

    float nc[5][5], np[5][5];
    const float* xb  = x  + (size_t)b * N_ * N_;
    const float* x1b = x1 + (size_t)b * N_ * N_;
    #pragma unroll
    for (int a = 0; a < 5; ++a) {
        int ri = min(max(i - 2 + a, 0), N_ - 1);
        #pragma unroll
        for (int c = 0; c < 5; ++c) {
            int ci = min(max(j - 2 + c, 0), N_ - 1);
            nc[a][c] = x1b[ri * N_ + ci];
            np[a][c] = xb[ri * N_ + ci] * 255.0f;
        }
    }

    float tot[16];
    #pragma unroll
    for (int k = 0; k < 16; ++k) tot[k] = 0.0f;

    for (int s = 0; s < 3; ++s) {
        const float* w  = samp1 + s * 36;
        const float* sb = sbias1 + s * 4;
        const char* lut = lut1q + (size_t)s * LUT_ROWS * 16;
        float rw[4];
        #pragma unroll
        for (int ch = 0; ch < 4; ++ch)
            rw[ch] = fminf(fmaxf(resw1[s * 4 + ch], 0.0f), 1.0f);

        float acc[16];
        #pragma unroll
        for (int k = 0; k < 16; ++k) acc[k] = 0.0f;

        #pragma unroll
        for (int r = 0; r < 4; ++r) {
            float vals[4];
            #pragma unroll
            for (int ch = 0; ch < 4; ++ch) {
                float vc = 0.0f, vp = 0.0f;
                #pragma unroll
                for (int di = 0; di < 3; ++di)
                    #pragma unroll
                    for (int dj = 0; dj < 3; ++dj) {
                        int pa, pb;
                        tapmap(r, di, dj, pa, pb);
                        float wt = w[ch * 9 + di * 3 + dj];
                        vc += wt * nc[pa][pb];
                        vp += wt * np[pa][pb];
                    }
                vc += sb[ch];
                vp += sb[ch];
                vals[ch] = rw[ch] * vp + (1.0f - rw[ch]) * vc;   // residual blend
            }
            Simplex sx = simplex4(vals[0], vals[1], vals[2], vals[3]);
            float oc[16];
            #pragma unroll
            for (int k = 0; k < 16; ++k) oc[k] = 0.0f;
            #pragma unroll
            for (int v = 0; v < 5; ++v) {
                const int4 q = *(const int4*)(lut + (size_t)sx.v[v] * 16);
                float p[16];
                unpack4(q.x, p); unpack4(q.y, p + 4);
                unpack4(q.z, p + 8); unpack4(q.w, p + 12);
                float wv = sx.w[v];
                #pragma unroll
                for (int k = 0; k < 16; ++k) oc[k] += wv * p[k];
            }
            // scatter rotated 4x4 sub-block into original-orientation accumulator
            #pragma unroll
            for (int u = 0; u < 4; ++u)
                #pragma unroll
                for (int v2 = 0; v2 < 4; ++v2) {
                    int k = 4 * u + v2;
                    int c = (r == 0) ? (4 * u + v2)
                          : (r == 1) ? (4 * (3 - v2) + u)
                          : (r == 2) ? (4 * (3 - u) + (3 - v2))
                                     : (4 * v2 + (3 - u));
                    acc[k] = rintf(acc[k] + oc[c] * 0.0625f);   // ste_round per rotation
                }
        }
        #pragma unroll
        for (int k = 0; k < 16; ++k) tot[k] += acc[k];
    }

    float* ob = out + (size_t)b * N4_ * N4_ + (size_t)(i * 4) * N4_ + (j * 4);
    #pragma unroll
    for (int u = 0; u < 4; ++u) {
        float4 val;
        val.x = rintf(fminf(fmaxf(tot[4 * u + 0] / 3.0f, 0.0f), 255.0f)) * (1.0f / 255.0f);
        val.y = rintf(fminf(fmaxf(tot[4 * u + 1] / 3.0f, 0.0f), 255.0f)) * (1.0f / 255.0f);
        val.z = rintf(fminf(fmaxf(tot[4 * u + 2] / 3.0f, 0.0f), 255.0f)) * (1.0f / 255.0f);
        val.w = rintf(fminf(fmaxf(tot[4 * u + 3] / 3.0f, 0.0f), 255.0f)) * (1.0f / 255.0f);
        *(float4*)(ob + (size_t)u * N4_) = val;
    }
}

extern "C" void kernel_launch(void* const* d_in, const int* in_sizes, int n_in,
                              void* d_out, int out_size, void* d_ws, size_t ws_size,
                              hipStream_t stream) {
    const float* x      = (const float*)d_in[0];
    const float* lut0   = (const float*)d_in[1];
    const float* lut1   = (const float*)d_in[2];
    const float* samp0  = (const float*)d_in[3];
    const float* samp1  = (const float*)d_in[4];
    const float* sbias0 = (const float*)d_in[5];
    const float* sbias1 = (const float*)d_in[6];
    const float* resw1  = (const float*)d_in[7];
    float* out = (float*)d_out;
    char* ws   = (char*)d_ws;

    const int N_L0 = 3 * LUT_ROWS;            // 250,563
    const int N_L1 = 3 * LUT_ROWS * 16;       // 4,009,008 (div by 4)
    size_t off_x1 = 0;                        // 4 MB of floats
    size_t off_l0 = (size_t)B_ * N_ * N_ * sizeof(float);
    size_t off_l1 = (off_l0 + N_L0 + 15) & ~(size_t)15;
    size_t need = off_l1 + N_L1;

    float* x1 = (float*)(ws + off_x1);
    char* l0q = ws + off_l0;
    char* l1q = ws + off_l1;

    const int threads = 256;
    const int grid = (B_ * N_ * N_) / threads;    // 4096
    (void)need; (void)ws_size;                    // need ~8.3 MB; ws is larger

    fix_lut0_kernel<<<(N_L0 + threads - 1) / threads, threads, 0, stream>>>(lut0, l0q, N_L0);
    fix_lut1_kernel<<<(N_L1 / 4 + threads - 1) / threads, threads, 0, stream>>>(
        (const float4*)lut1, (char4*)l1q, N_L1 / 4);
    stage0_kernel<<<grid, threads, 0, stream>>>(x, l0q, samp0, sbias0, x1);
    stage1_kernel<<<grid, threads, 0, stream>>>(x, x1, l1q, samp1, sbias1, resw1, out);
}

// Round 4
// 301.668 us; speedup vs baseline: 5.4383x; 1.2277x over previous
//
#include <hip/hip_runtime.h>
#include <math.h>

// AutoLUT forward, MI355X. B=4, N=512, K=3 (PAD=2), Q=16, L=17, UPSCALE=4, SAMPLERS=3.
// R4: tap-outer conv (2 live pixels + 32 accum regs instead of 50-reg neighborhoods)
//     to cut VGPR below 128 -> 4 waves/SIMD; 0.0625 folded into simplex weights.
static constexpr int B_ = 4;
static constexpr int N_ = 512;
static constexpr int N4_ = 2048;
static constexpr int LUT_ROWS = 83521;         // 17^4
static constexpr int ST0 = 4913, ST1 = 289, ST2 = 17, ST3 = 1;

__device__ __forceinline__ float fixw(float v) {
    v = rintf(v * 127.0f);
    return fminf(fmaxf(v, -127.0f), 127.0f);
}

__global__ void fix_lut0_kernel(const float* __restrict__ in, char* __restrict__ out, int n) {
    int t = blockIdx.x * blockDim.x + threadIdx.x;
    if (t < n) out[t] = (char)(int)fixw(in[t]);
}

__global__ void fix_lut1_kernel(const float4* __restrict__ in, char4* __restrict__ out, int n4) {
    int t = blockIdx.x * blockDim.x + threadIdx.x;
    if (t < n4) {
        float4 v = in[t];
        char4 o;
        o.x = (char)(int)fixw(v.x);
        o.y = (char)(int)fixw(v.y);
        o.z = (char)(int)fixw(v.z);
        o.w = (char)(int)fixw(v.w);
        out[t] = o;
    }
}

struct Simplex {
    int v[5];
    float w[5];   // pre-scaled by 1/16
};

// 4-D simplex lookup setup. floor/mod by 16 are exact in fp32 (pow-2); sort is a
// stable descending bubble network (ties -> zero-weight vertices, order-irrelevant).
__device__ __forceinline__ Simplex simplex4(float a, float b, float c, float d) {
    float fl0 = floorf(a * 0.0625f), fl1 = floorf(b * 0.0625f),
          fl2 = floorf(c * 0.0625f), fl3 = floorf(d * 0.0625f);
    float f[4] = { a - 16.0f * fl0, b - 16.0f * fl1, c - 16.0f * fl2, d - 16.0f * fl3 };
    int l0 = min(max((int)fl0, 0), 15);
    int l1 = min(max((int)fl1, 0), 15);
    int l2 = min(max((int)fl2, 0), 15);
    int l3 = min(max((int)fl3, 0), 15);
    int st[4] = { ST0, ST1, ST2, ST3 };
#define CSW(A, Bq) { if (f[A] < f[Bq]) { float tf = f[A]; f[A] = f[Bq]; f[Bq] = tf; \
                                         int ts = st[A]; st[A] = st[Bq]; st[Bq] = ts; } }
    CSW(0, 1) CSW(1, 2) CSW(2, 3) CSW(0, 1) CSW(1, 2) CSW(0, 1)
#undef CSW
    Simplex s;
    s.v[0] = l0 * ST0 + l1 * ST1 + l2 * ST2 + l3;
    s.v[1] = s.v[0] + st[0];
    s.v[2] = s.v[1] + st[1];
    s.v[3] = s.v[2] + st[2];
    s.v[4] = s.v[3] + st[3];
    s.w[0] = (16.0f - f[0]) * 0.0625f;
    s.w[1] = (f[0] - f[1]) * 0.0625f;
    s.w[2] = (f[1] - f[2]) * 0.0625f;
    s.w[3] = (f[2] - f[3]) * 0.0625f;
    s.w[4] = f[3] * 0.0625f;
    return s;
}

// Inverse tap map: which (di,dj) of rotation r reads clamped-neighborhood tap (a,c).
// (rotation r + edge-pad + VALID conv + rotate-back == clamped reads, orig frame)
__device__ __forceinline__ bool tap_for_r(int r, int a, int c, int& di, int& dj) {
    if (r == 0) { di = a - 2; dj = c - 2; return (a >= 2) && (c >= 2); }
    if (r == 1) { di = 2 - c; dj = a - 2; return (a >= 2) && (c <= 2); }
    if (r == 2) { di = 2 - a; dj = 2 - c; return (a <= 2) && (c <= 2); }
    di = c - 2; dj = 2 - a; return (a <= 2) && (c >= 2);
}

__device__ __forceinline__ void unpack4(int w, float* o) {
    o[0] = (float)((w << 24) >> 24);
    o[1] = (float)((w << 16) >> 24);
    o[2] = (float)((w << 8) >> 24);
    o[3] = (float)(w >> 24);
}

__global__ __launch_bounds__(256) void stage0_kernel(
    const float* __restrict__ x,       // (4,512,512), [0,1]
    const char* __restrict__ lut0q,    // (3,83521) int8 fixed
    const float* __restrict__ samp0,   // (3,4,3,3)
    const float* __restrict__ sbias0,  // (3,4)
    float* __restrict__ x1)            // out: (4,512,512), integer-valued 0..255
{
    int tid = blockIdx.x * blockDim.x + threadIdx.x;
    if (tid >= B_ * N_ * N_) return;
    int j = tid & (N_ - 1);
    int i = (tid >> 9) & (N_ - 1);
    int b = tid >> 18;
    const float* xb = x + (size_t)b * N_ * N_;

    float pred = 0.0f;
    for (int s = 0; s < 3; ++s) {
        const float* w  = samp0 + s * 36;
        const float* sb = sbias0 + s * 4;
        const char* lut = lut0q + (size_t)s * LUT_ROWS;

        // tap-outer conv: only 1 pixel + 16 accumulators live
        float vals[4][4];
        #pragma unroll
        for (int r = 0; r < 4; ++r)
            #pragma unroll
            for (int ch = 0; ch < 4; ++ch) vals[r][ch] = 0.0f;
        #pragma unroll
        for (int a = 0; a < 5; ++a) {
            int ri = min(max(i - 2 + a, 0), N_ - 1);
            #pragma unroll
            for (int c = 0; c < 5; ++c) {
                int ci = min(max(j - 2 + c, 0), N_ - 1);
                float px = xb[ri * N_ + ci] * 255.0f;
                #pragma unroll
                for (int r = 0; r < 4; ++r) {
                    int di, dj;
                    if (tap_for_r(r, a, c, di, dj)) {
                        #pragma unroll
                        for (int ch = 0; ch < 4; ++ch)
                            vals[r][ch] += w[ch * 9 + di * 3 + dj] * px;
                    }
                }
            }
        }

        float acc = 0.0f;
        #pragma unroll
        for (int r = 0; r < 4; ++r) {
            Simplex sx = simplex4(vals[r][0] + sb[0], vals[r][1] + sb[1],
                                  vals[r][2] + sb[2], vals[r][3] + sb[3]);
            float o = 0.0f;
            #pragma unroll
            for (int v = 0; v < 5; ++v)
                o += sx.w[v] * (float)lut[sx.v[v]];
            acc = rintf(acc + o);   // ste_round after each rotation
        }
        pred += acc;
    }
    x1[tid] = rintf(fminf(fmaxf(pred / 12.0f + 127.0f, 0.0f), 255.0f));
}

__global__ __launch_bounds__(256) void stage1_kernel(
    const float* __restrict__ x,       // original (4,512,512), [0,1]
    const float* __restrict__ x1,      // stage-0 out, 0..255
    const char* __restrict__ lut1q,    // (3,83521,16) int8 fixed
    const float* __restrict__ samp1,   // (3,4,3,3)
    const float* __restrict__ sbias1,  // (3,4)
    const float* __restrict__ resw1,   // (3,2,2)
    float* __restrict__ out)           // (4,2048,2048)
{
    int tid = blockIdx.x * blockDim.x + threadIdx.x;
    if (tid >= B_ * N_ * N_) return;
    int j = tid & (N_ - 1);
    int i = (tid >> 9) & (N_ - 1);
    int b = tid >> 18;
    const float* xb  = x  + (size_t)b * N_ * N_;
    const float* x1b = x1 + (size_t)b * N_ * N_;

    float tot[16];
    #pragma unroll
    for (int k = 0; k < 16; ++k) tot[k] = 0.0f;

    for (int s = 0; s < 3; ++s) {
        const float* w  = samp1 + s * 36;
        const float* sb = sbias1 + s * 4;
        const char* lut = lut1q + (size_t)s * LUT_ROWS * 16;
        float rw[4];
        #pragma unroll
        for (int ch = 0; ch < 4; ++ch)
            rw[ch] = fminf(fmaxf(resw1[s * 4 + ch], 0.0f), 1.0f);

        // ---- tap-outer conv: 2 live pixels + 32 accumulators (vc, vp)
        float vc[4][4], vp[4][4];
        #pragma unroll
        for (int r = 0; r < 4; ++r)
            #pragma unroll
            for (int ch = 0; ch < 4; ++ch) { vc[r][ch] = 0.0f; vp[r][ch] = 0.0f; }
        #pragma unroll
        for (int a = 0; a < 5; ++a) {
            int ri = min(max(i - 2 + a, 0), N_ - 1);
            #pragma unroll
            for (int c = 0; c < 5; ++c) {
                int ci = min(max(j - 2 + c, 0), N_ - 1);
                float pc = x1b[ri * N_ + ci];
                float pp = xb[ri * N_ + ci] * 255.0f;
                #pragma unroll
                for (int r = 0; r < 4; ++r) {
                    int di, dj;
                    if (tap_for_r(r, a, c, di, dj)) {
                        #pragma unroll
                        for (int ch = 0; ch < 4; ++ch) {
                            float wt = w[ch * 9 + di * 3 + dj];
                            vc[r][ch] += wt * pc;
                            vp[r][ch] += wt * pp;
                        }
                    }
                }
            }
        }

        // ---- gather/interp phase
        float acc[16];
        #pragma unroll
        for (int k = 0; k < 16; ++k) acc[k] = 0.0f;

        #pragma unroll
        for (int r = 0; r < 4; ++r) {
            float vals[4];
            #pragma unroll
            for (int ch = 0; ch < 4; ++ch)
                vals[ch] = rw[ch] * (vp[r][ch] + sb[ch])
                         + (1.0f - rw[ch]) * (vc[r][ch] + sb[ch]);
            Simplex sx = simplex4(vals[0], vals[1], vals[2], vals[3]);
            float oc[16];
            #pragma unroll
            for (int k = 0; k < 16; ++k) oc[k] = 0.0f;
            #pragma unroll
            for (int v = 0; v < 5; ++v) {
                const int4 q = *(const int4*)(lut + (size_t)sx.v[v] * 16);
                float p[16];
                unpack4(q.x, p); unpack4(q.y, p + 4);
                unpack4(q.z, p + 8); unpack4(q.w, p + 12);
                float wv = sx.w[v];
                #pragma unroll
                for (int k = 0; k < 16; ++k) oc[k] += wv * p[k];
            }
            // scatter rotated 4x4 sub-block into original-orientation accumulator
            #pragma unroll
            for (int u = 0; u < 4; ++u)
                #pragma unroll
                for (int v2 = 0; v2 < 4; ++v2) {
                    int k = 4 * u + v2;
                    int c = (r == 0) ? (4 * u + v2)
                          : (r == 1) ? (4 * (3 - v2) + u)
                          : (r == 2) ? (4 * (3 - u) + (3 - v2))
                                     : (4 * v2 + (3 - u));
                    acc[k] = rintf(acc[k] + oc[c]);   // ste_round per rotation
                }
        }
        #pragma unroll
        for (int k = 0; k < 16; ++k) tot[k] += acc[k];
    }

    float* ob = out + (size_t)b * N4_ * N4_ + (size_t)(i * 4) * N4_ + (j * 4);
    #pragma unroll
    for (int u = 0; u < 4; ++u) {
        float4 val;
        val.x = rintf(fminf(fmaxf(tot[4 * u + 0] / 3.0f, 0.0f), 255.0f)) * (1.0f / 255.0f);
        val.y = rintf(fminf(fmaxf(tot[4 * u + 1] / 3.0f, 0.0f), 255.0f)) * (1.0f / 255.0f);
        val.z = rintf(fminf(fmaxf(tot[4 * u + 2] / 3.0f, 0.0f), 255.0f)) * (1.0f / 255.0f);
        val.w = rintf(fminf(fmaxf(tot[4 * u + 3] / 3.0f, 0.0f), 255.0f)) * (1.0f / 255.0f);
        *(float4*)(ob + (size_t)u * N4_) = val;
    }
}

extern "C" void kernel_launch(void* const* d_in, const int* in_sizes, int n_in,
                              void* d_out, int out_size, void* d_ws, size_t ws_size,
                              hipStream_t stream) {
    const float* x      = (const float*)d_in[0];
    const float* lut0   = (const float*)d_in[1];
    const float* lut1   = (const float*)d_in[2];
    const float* samp0  = (const float*)d_in[3];
    const float* samp1  = (const float*)d_in[4];
    const float* sbias0 = (const float*)d_in[5];
    const float* sbias1 = (const float*)d_in[6];
    const float* resw1  = (const float*)d_in[7];
    float* out = (float*)d_out;
    char* ws   = (char*)d_ws;

    const int N_L0 = 3 * LUT_ROWS;            // 250,563
    const int N_L1 = 3 * LUT_ROWS * 16;       // 4,009,008 (div by 4)
    size_t off_x1 = 0;                        // 4 MB of floats
    size_t off_l0 = (size_t)B_ * N_ * N_ * sizeof(float);
    size_t off_l1 = (off_l0 + N_L0 + 15) & ~(size_t)15;

    float* x1 = (float*)(ws + off_x1);
    char* l0q = ws + off_l0;
    char* l1q = ws + off_l1;

    const int threads = 256;
    const int grid = (B_ * N_ * N_) / threads;    // 4096

    fix_lut0_kernel<<<(N_L0 + threads - 1) / threads, threads, 0, stream>>>(lut0, l0q, N_L0);
    fix_lut1_kernel<<<(N_L1 / 4 + threads - 1) / threads, threads, 0, stream>>>(
        (const float4*)lut1, (char4*)l1q, N_L1 / 4);
    stage0_kernel<<<grid, threads, 0, stream>>>(x, l0q, samp0, sbias0, x1);
    stage1_kernel<<<grid, threads, 0, stream>>>(x, x1, l1q, samp1, sbias1, resw1, out);
}